// Round 6
// baseline (3894.930 us; speedup 1.0000x reference)
//
#include <hip/hip_runtime.h>
#include <hip/hip_bf16.h>
#include <math.h>

// ---------------------------------------------------------------------------
// TransformerBlock for MI355X (gfx950) — split-bf16 MFMA GEMMs, packed format.
// Shapes: B=2, S=2048, D=2048, H=16, dk=128, DFF=5632. fp32 in/out.
//
// Numeric trick: x = hi(bf16) + lo(bf16), stored PACKED in one u32
// (hi<<16 | lo) — same bytes as fp32. GEMM computes
//   A*B ~= Ah*Bh + Ah*Bl + Al*Bh   (drops lo*lo ~ 2^-18)
// via bf16 MFMA -> ~1e-6 relative error, ~3x faster than fp32 vector path.
// Activations are produced packed by rmsnorm/attention (fused, free); the
// SiLU*gate product is produced packed by the W3-GEMM epilogue (fused).
// Weights are read as raw fp32 and split in-register during LDS staging.
// No global_load_lds, no inline asm. Workspace ~135 MB.
// This round adds: XCD-aware block swizzle (T1) in gemm_pk — bijective
// (grids 512 / 1408 blocks, both %8==0), guarded, perf-only.
// ---------------------------------------------------------------------------

#define EPSF 1e-5f

typedef __attribute__((ext_vector_type(4))) float f32x4;
typedef __attribute__((ext_vector_type(8))) short s16x8;
typedef __attribute__((ext_vector_type(4))) unsigned short u16x4;
typedef __attribute__((ext_vector_type(4))) unsigned int u32x4;
typedef unsigned short u16;
typedef unsigned int u32;

__device__ __forceinline__ u16 f2bf(float f) {  // round-to-nearest-even
    u32 u = __float_as_uint(f);
    return (u16)((u + 0x7fffu + ((u >> 16) & 1u)) >> 16);
}
__device__ __forceinline__ float bf2f(u16 b) {
    return __uint_as_float(((u32)b) << 16);
}
__device__ __forceinline__ u32 packsplit(float f) {  // (hi<<16)|lo
    const u16 h = f2bf(f);
    const u16 l = f2bf(f - bf2f(h));
    return ((u32)h << 16) | (u32)l;
}

// ---------------- RMSNorm -> packed split-bf16 (one block/row, D=2048) ------
__global__ __launch_bounds__(256) void rmsnorm_pack_k(const float* __restrict__ X,
                                                      const float* __restrict__ g,
                                                      u32* __restrict__ Yp) {
    const int row = blockIdx.x;
    const int tid = threadIdx.x;
    const float* x = X + (size_t)row * 2048;

    float4 v0 = *(const float4*)&x[tid * 8];
    float4 v1 = *(const float4*)&x[tid * 8 + 4];
    float ss = v0.x * v0.x + v0.y * v0.y + v0.z * v0.z + v0.w * v0.w +
               v1.x * v1.x + v1.y * v1.y + v1.z * v1.z + v1.w * v1.w;
    #pragma unroll
    for (int o = 32; o > 0; o >>= 1) ss += __shfl_xor(ss, o);
    __shared__ float wsum[4];
    if ((tid & 63) == 0) wsum[tid >> 6] = ss;
    __syncthreads();
    const float inv = 1.0f / sqrtf((wsum[0] + wsum[1] + wsum[2] + wsum[3]) *
                                   (1.0f / 2048.0f) + EPSF);

    float4 ga = *(const float4*)&g[tid * 8];
    float4 gb = *(const float4*)&g[tid * 8 + 4];
    const float y[8] = {v0.x * ga.x * inv, v0.y * ga.y * inv, v0.z * ga.z * inv,
                        v0.w * ga.w * inv, v1.x * gb.x * inv, v1.y * gb.y * inv,
                        v1.z * gb.z * inv, v1.w * gb.w * inv};
    u32x4 p0, p1;
    p0.x = packsplit(y[0]); p0.y = packsplit(y[1]);
    p0.z = packsplit(y[2]); p0.w = packsplit(y[3]);
    p1.x = packsplit(y[4]); p1.y = packsplit(y[5]);
    p1.z = packsplit(y[6]); p1.w = packsplit(y[7]);
    const size_t base = (size_t)row * 2048 + tid * 8;
    *(u32x4*)&Yp[base] = p0;
    *(u32x4*)&Yp[base + 4] = p1;
}

// ---------------- MFMA GEMM: C[M,N] = A[M,K] * B[N,K]^T -------------------
// A: packed split-bf16 u32 [M,K]. B: fp32 [N,K] (split in-register at stage).
// 128x128 tile, BK=32, 256 thr = 4 waves (2x2 of 64x64), 16x16x32 bf16 MFMA,
// 3 MFMAs per fragment pair (hh, hl, lh).
// EPI=0: C[idx] = acc (+ R[idx] if R)          (C fp32 out)
// EPI=1: a=C[idx] (fp32); ((u32*)C)[idx] = packsplit(silu(a)*acc)  [R unused]
template<int EPI>
__global__ __launch_bounds__(256) void gemm_pk(const u32* __restrict__ Ap,
                                               const float* __restrict__ B,
                                               const float* __restrict__ R,
                                               float* __restrict__ C,
                                               int M, int N, int K) {
    __shared__ __align__(16) u16 sAh[4096];  // [128 rows][32 k]
    __shared__ __align__(16) u16 sAl[4096];
    __shared__ __align__(16) u16 sBh[4096];
    __shared__ __align__(16) u16 sBl[4096];
    const int tid = threadIdx.x;
    const int wid = tid >> 6, lane = tid & 63;

    // XCD-aware swizzle (T1, m192): MI355X dispatches consecutive blocks to
    // XCDs round-robin; remap so each XCD owns a contiguous band of tiles
    // (shared A-panels stay in its private L2). Bijective iff nwg%8==0.
    int bx = blockIdx.x, by = blockIdx.y;
    {
        const int nwg = gridDim.x * gridDim.y;
        if ((nwg & 7) == 0) {
            const int wgid = by * gridDim.x + bx;
            const int chunk = nwg >> 3;
            const int swz = (wgid & 7) * chunk + (wgid >> 3);
            bx = swz % gridDim.x;
            by = swz / gridDim.x;
        }
    }
    const int m0 = by * 128, n0 = bx * 128;
    const int wm = wid >> 1, wn = wid & 1;
    const int lr = lane & 15;          // fragment row (A) / col (B)
    const int lk = (lane >> 4) * 8;    // k-octet

    f32x4 acc[4][4];
    #pragma unroll
    for (int i = 0; i < 4; ++i)
        #pragma unroll
        for (int j = 0; j < 4; ++j) {
            acc[i][j].x = 0.f; acc[i][j].y = 0.f;
            acc[i][j].z = 0.f; acc[i][j].w = 0.f;
        }

    // staging: 1024 16B-chunks per tile; thread covers f = tid + 256*j
    // (row = f>>3, 4 elems at col (f&7)*4) -> coalesced 16B/lane.
    u32x4 pa[4];
    f32x4 vb[4];
    #pragma unroll
    for (int j = 0; j < 4; ++j) {
        const int f = tid + 256 * j, row = f >> 3, c4 = (f & 7) * 4;
        pa[j] = *(const u32x4*)&Ap[(size_t)(m0 + row) * K + c4];
        vb[j] = *(const f32x4*)&B[(size_t)(n0 + row) * K + c4];
    }

    const int nk = K / 32;
    for (int kt = 0; kt < nk; ++kt) {
        // regs -> LDS (unpack A, split B)
        #pragma unroll
        for (int j = 0; j < 4; ++j) {
            const int f = tid + 256 * j, row = f >> 3, c4 = (f & 7) * 4;
            const u32x4 p = pa[j];
            u16x4 ah, al;
            ah.x = (u16)(p.x >> 16); al.x = (u16)(p.x & 0xFFFFu);
            ah.y = (u16)(p.y >> 16); al.y = (u16)(p.y & 0xFFFFu);
            ah.z = (u16)(p.z >> 16); al.z = (u16)(p.z & 0xFFFFu);
            ah.w = (u16)(p.w >> 16); al.w = (u16)(p.w & 0xFFFFu);
            *(u16x4*)&sAh[row * 32 + c4] = ah;
            *(u16x4*)&sAl[row * 32 + c4] = al;
            const f32x4 v = vb[j];
            u16x4 bh, bl;
            bh.x = f2bf(v.x); bl.x = f2bf(v.x - bf2f(bh.x));
            bh.y = f2bf(v.y); bl.y = f2bf(v.y - bf2f(bh.y));
            bh.z = f2bf(v.z); bl.z = f2bf(v.z - bf2f(bh.z));
            bh.w = f2bf(v.w); bl.w = f2bf(v.w - bf2f(bh.w));
            *(u16x4*)&sBh[row * 32 + c4] = bh;
            *(u16x4*)&sBl[row * 32 + c4] = bl;
        }
        __syncthreads();

        // prefetch next K-tile into regs (global latency hides under MFMA)
        if (kt + 1 < nk) {
            const int k0 = (kt + 1) * 32;
            #pragma unroll
            for (int j = 0; j < 4; ++j) {
                const int f = tid + 256 * j, row = f >> 3, c4 = (f & 7) * 4;
                pa[j] = *(const u32x4*)&Ap[(size_t)(m0 + row) * K + k0 + c4];
                vb[j] = *(const f32x4*)&B[(size_t)(n0 + row) * K + k0 + c4];
            }
        }

        // LDS -> fragments (A: row=lane&15, k=(lane>>4)*8+e; B: col likewise)
        s16x8 fah[4], fal[4], fbh[4], fbl[4];
        #pragma unroll
        for (int i = 0; i < 4; ++i) {
            const int ra = (wm * 64 + i * 16 + lr) * 32 + lk;
            const int rb = (wn * 64 + i * 16 + lr) * 32 + lk;
            fah[i] = *(const s16x8*)&sAh[ra];
            fal[i] = *(const s16x8*)&sAl[ra];
            fbh[i] = *(const s16x8*)&sBh[rb];
            fbl[i] = *(const s16x8*)&sBl[rb];
        }
        #pragma unroll
        for (int i = 0; i < 4; ++i)
            #pragma unroll
            for (int j = 0; j < 4; ++j) {
                acc[i][j] = __builtin_amdgcn_mfma_f32_16x16x32_bf16(fah[i], fbh[j], acc[i][j], 0, 0, 0);
                acc[i][j] = __builtin_amdgcn_mfma_f32_16x16x32_bf16(fah[i], fbl[j], acc[i][j], 0, 0, 0);
                acc[i][j] = __builtin_amdgcn_mfma_f32_16x16x32_bf16(fal[i], fbh[j], acc[i][j], 0, 0, 0);
            }
        __syncthreads();
    }

    // C/D layout (m89/m91): col = lane&15, row = (lane>>4)*4 + reg
    const int orow = (lane >> 4) * 4, ocol = lane & 15;
    #pragma unroll
    for (int i = 0; i < 4; ++i)
        #pragma unroll
        for (int j = 0; j < 4; ++j) {
            const int col = n0 + wn * 64 + j * 16 + ocol;
            #pragma unroll
            for (int rI = 0; rI < 4; ++rI) {
                const int row = m0 + wm * 64 + i * 16 + orow + rI;
                const size_t idx = (size_t)row * N + col;
                const float v = acc[i][j][rI];
                if (EPI == 0) {
                    C[idx] = R ? v + R[idx] : v;
                } else {
                    // gate value = v; a value read from C (fp32), product
                    // written packed IN PLACE (same thread, same address).
                    const float aval = C[idx];
                    const float prod = aval / (1.f + __expf(-aval)) * v;
                    ((u32*)C)[idx] = packsplit(prod);
                }
            }
        }
}

// ---------------- RoPE table ------------------------------------------------
__global__ __launch_bounds__(256) void rope_table_k(float2* __restrict__ tab, int S) {
    const int idx = blockIdx.x * blockDim.x + threadIdx.x;
    if (idx >= S * 64) return;
    const int s = idx >> 6;
    const int i = idx & 63;
    const float inv_freq = (float)(1.0 / pow(10000.0, (double)(2 * i) / 128.0));
    const float a = (float)s * inv_freq;
    tab[idx] = make_float2(sinf(a), cosf(a));
}

// ---------------- RoPE apply (in place, fp32) -------------------------------
__global__ __launch_bounds__(256) void rope_apply_k(float* __restrict__ X,
                                                    const float2* __restrict__ tab,
                                                    int S) {
    const int idx = blockIdx.x * blockDim.x + threadIdx.x;  // over B*S*H*64
    const int i = idx & 63;
    const int h = (idx >> 6) & 15;
    const int bs = idx >> 10;
    const int s = bs & (S - 1);
    const float2 sc = tab[s * 64 + i];
    const size_t base = (size_t)bs * 2048 + h * 128 + 2 * i;
    float2 v = *(float2*)&X[base];
    float2 o;
    o.x = v.x * sc.y - v.y * sc.x;
    o.y = v.x * sc.x + v.y * sc.y;
    *(float2*)&X[base] = o;
}

// ---------------- Causal flash attention (fp32), packed output --------------
#define BQ 32
#define BKT 32

__global__ __launch_bounds__(256) void flash_attn_k(const float* __restrict__ Q,
                                                    const float* __restrict__ K,
                                                    const float* __restrict__ V,
                                                    u32* __restrict__ Op,
                                                    int S, int H) {
    __shared__ __align__(16) float Ks[BKT][128];
    __shared__ __align__(16) float Vs[BKT][128];
    const int tid = threadIdx.x;
    const int q0 = blockIdx.x * BQ;
    const int bh = blockIdx.y;
    const int b = bh / H, h = bh % H;
    const float scale = 0.088388347648318447f;  // 1/sqrt(128)
    const size_t headoff = (size_t)b * S * 2048 + (size_t)h * 128;

    const int r = tid >> 3;
    const int g = tid & 7;
    const int qrow = q0 + r;

    float q[16], acc[16];
    {
        const float* qp = Q + headoff + (size_t)qrow * 2048 + g * 16;
        #pragma unroll
        for (int t = 0; t < 4; ++t) {
            float4 v = *(const float4*)(qp + t * 4);
            q[t * 4 + 0] = v.x; q[t * 4 + 1] = v.y;
            q[t * 4 + 2] = v.z; q[t * 4 + 3] = v.w;
        }
    }
    #pragma unroll
    for (int j = 0; j < 16; ++j) acc[j] = 0.f;
    float m = -INFINITY, l = 0.f;

    for (int k0 = 0; k0 <= q0; k0 += BKT) {
        {
            const int row = tid >> 3;
            const int c = (tid & 7) * 16;
            const float* kp = K + headoff + (size_t)(k0 + row) * 2048 + c;
            const float* vp = V + headoff + (size_t)(k0 + row) * 2048 + c;
            #pragma unroll
            for (int t = 0; t < 4; ++t) {
                *(float4*)&Ks[row][c + t * 4] = *(const float4*)(kp + t * 4);
                *(float4*)&Vs[row][c + t * 4] = *(const float4*)(vp + t * 4);
            }
        }
        __syncthreads();

        float p[BKT];
        float tmax = -INFINITY;
        #pragma unroll
        for (int k = 0; k < BKT; ++k) {
            float s = 0.f;
            const float* kr = &Ks[k][g * 16];
            #pragma unroll
            for (int j = 0; j < 16; ++j) s = fmaf(q[j], kr[j], s);
            s += __shfl_xor(s, 1);
            s += __shfl_xor(s, 2);
            s += __shfl_xor(s, 4);
            s *= scale;
            if (k0 + k > qrow) s = -INFINITY;
            p[k] = s;
            tmax = fmaxf(tmax, s);
        }
        const float mnew = fmaxf(m, tmax);
        const float corr = __expf(m - mnew);  // m=-inf first tile -> 0
        float lsum = 0.f;
        #pragma unroll
        for (int k = 0; k < BKT; ++k) {
            const float pe = __expf(p[k] - mnew);  // masked -> 0
            p[k] = pe;
            lsum += pe;
        }
        l = l * corr + lsum;
        #pragma unroll
        for (int j = 0; j < 16; ++j) acc[j] *= corr;
        #pragma unroll
        for (int k = 0; k < BKT; ++k) {
            const float pk = p[k];
            const float* vr = &Vs[k][g * 16];
            #pragma unroll
            for (int j = 0; j < 16; ++j) acc[j] = fmaf(pk, vr[j], acc[j]);
        }
        m = mnew;
        __syncthreads();
    }

    const float inv_l = 1.0f / l;
    u32* op = Op + headoff + (size_t)qrow * 2048 + g * 16;
    #pragma unroll
    for (int t = 0; t < 4; ++t) {
        u32x4 pv;
        pv.x = packsplit(acc[t * 4 + 0] * inv_l);
        pv.y = packsplit(acc[t * 4 + 1] * inv_l);
        pv.z = packsplit(acc[t * 4 + 2] * inv_l);
        pv.w = packsplit(acc[t * 4 + 3] * inv_l);
        *(u32x4*)(op + t * 4) = pv;
    }
}

// ---------------------------------------------------------------------------
extern "C" void kernel_launch(void* const* d_in, const int* in_sizes, int n_in,
                              void* d_out, int out_size, void* d_ws, size_t ws_size,
                              hipStream_t stream) {
    (void)in_sizes; (void)n_in; (void)out_size; (void)ws_size;
    const float* x  = (const float*)d_in[0];
    const float* Wq = (const float*)d_in[1];
    const float* Wk = (const float*)d_in[2];
    const float* Wv = (const float*)d_in[3];
    const float* Wo = (const float*)d_in[4];
    const float* W1 = (const float*)d_in[5];
    const float* W2 = (const float*)d_in[6];
    const float* W3 = (const float*)d_in[7];
    const float* g1 = (const float*)d_in[8];
    const float* g2 = (const float*)d_in[9];
    float* out = (float*)d_out;

    constexpr int Bt = 2, S = 2048, Dm = 2048, Hh = 16, Dff = 5632;
    constexpr int M = Bt * S;                  // 4096
    constexpr size_t MD = (size_t)M * Dm;      // 8.39M elems

    // -------- workspace (~135 MB total) ------------------------------------
    char* w = (char*)d_ws;
    size_t off = 0;
    auto alloc = [&](size_t bytes) -> void* {
        void* p = w + off;
        off += (bytes + 255) & ~(size_t)255;
        return p;
    };
    u32*   xnp = (u32*)alloc(MD * 4);      // 33.6 MB; also ctx (packed)
    float* Qb  = (float*)alloc(MD * 4);    // 33.6 MB \  reused as FFN 'a'
    float* Kb  = (float*)alloc(MD * 4);    // 33.6 MB  | buffer (92.3 MB <=
    float* Vb  = (float*)alloc(MD * 4);    // 33.6 MB /  100.7 MB of Q+K+V)
    float2* tab = (float2*)alloc((size_t)S * 64 * 8);  // 1 MB
    u32*   ctxp = xnp;                     // attn out over xn (dead post-QKV)
    float* ab   = Qb;                      // FFN 'a' over Q/K/V (dead post-attn)
    u32*   abp  = (u32*)Qb;                // silu product packed over 'a'

    // 1. rmsnorm(x, g1) -> xnp (packed)
    rmsnorm_pack_k<<<M, 256, 0, stream>>>(x, g1, xnp);

    // 2. Q/K/V = xn @ W^T (fp32 out)
    dim3 gqkv(Dm / 128, M / 128);
    gemm_pk<0><<<gqkv, 256, 0, stream>>>(xnp, Wq, nullptr, Qb, M, Dm, Dm);
    gemm_pk<0><<<gqkv, 256, 0, stream>>>(xnp, Wk, nullptr, Kb, M, Dm, Dm);
    gemm_pk<0><<<gqkv, 256, 0, stream>>>(xnp, Wv, nullptr, Vb, M, Dm, Dm);

    // 3. RoPE on Q, K
    rope_table_k<<<(S * 64) / 256, 256, 0, stream>>>(tab, S);
    const int ropeN = M * Hh * 64;
    rope_apply_k<<<ropeN / 256, 256, 0, stream>>>(Qb, tab, S);
    rope_apply_k<<<ropeN / 256, 256, 0, stream>>>(Kb, tab, S);

    // 4. causal flash attention -> ctxp (packed, merged-head [B*S, D])
    flash_attn_k<<<dim3(S / BQ, Bt * Hh), 256, 0, stream>>>(Qb, Kb, Vb, ctxp, S, Hh);

    // 5. x2 = x + ctx @ Wo^T -> out
    gemm_pk<0><<<gqkv, 256, 0, stream>>>(ctxp, Wo, x, out, M, Dm, Dm);

    // 6. rmsnorm(x2, g2) -> xnp (ctx dead)
    rmsnorm_pack_k<<<M, 256, 0, stream>>>(out, g2, xnp);

    // 7. FFN a = xn @ W1^T (fp32, over dead Q/K/V region)
    dim3 gff(Dff / 128, M / 128);
    gemm_pk<0><<<gff, 256, 0, stream>>>(xnp, W1, nullptr, ab, M, Dff, Dm);

    // 8. gate = xn @ W3^T with fused epilogue:
    //    reads a[idx] (fp32), writes packsplit(silu(a)*gate) in place.
    gemm_pk<1><<<gff, 256, 0, stream>>>(xnp, W3, nullptr, ab, M, Dff, Dm);

    // 9. out = x2 + product @ W2^T (in-place residual)
    gemm_pk<0><<<gqkv, 256, 0, stream>>>(abp, W2, out, out, M, Dm, Dff);
}

// Round 7
// 2019.370 us; speedup vs baseline: 1.9288x; 1.9288x over previous
//
#include <hip/hip_runtime.h>
#include <hip/hip_bf16.h>
#include <math.h>

// ---------------------------------------------------------------------------
// TransformerBlock for MI355X (gfx950) — split-bf16 MFMA GEMMs + MFMA flash
// attention, packed format. Shapes: B=2,S=2048,D=2048,H=16,dk=128,DFF=5632.
//
// Numeric trick: x = hi(bf16)+lo(bf16), PACKED in one u32 (hi<<16|lo).
// GEMM/attention compute A*B ~= Ah*Bh + Ah*Bl + Al*Bh via bf16 MFMA
// (~1e-6 rel err). Activations produced packed by producers (fused).
// V is written by its GEMM epilogue directly as packed TRANSPOSED
// Vt[bh][d][s] so attention needs no in-kernel transpose.
// ---------------------------------------------------------------------------

#define EPSF 1e-5f

typedef __attribute__((ext_vector_type(4))) float f32x4;
typedef __attribute__((ext_vector_type(8))) short s16x8;
typedef __attribute__((ext_vector_type(4))) unsigned short u16x4;
typedef __attribute__((ext_vector_type(4))) unsigned int u32x4;
typedef unsigned short u16;
typedef unsigned int u32;

__device__ __forceinline__ u16 f2bf(float f) {  // round-to-nearest-even
    u32 u = __float_as_uint(f);
    return (u16)((u + 0x7fffu + ((u >> 16) & 1u)) >> 16);
}
__device__ __forceinline__ float bf2f(u16 b) {
    return __uint_as_float(((u32)b) << 16);
}
__device__ __forceinline__ u32 packsplit(float f) {  // (hi<<16)|lo
    const u16 h = f2bf(f);
    const u16 l = f2bf(f - bf2f(h));
    return ((u32)h << 16) | (u32)l;
}

// ---------------- RMSNorm -> packed split-bf16 (one block/row, D=2048) ------
__global__ __launch_bounds__(256) void rmsnorm_pack_k(const float* __restrict__ X,
                                                      const float* __restrict__ g,
                                                      u32* __restrict__ Yp) {
    const int row = blockIdx.x;
    const int tid = threadIdx.x;
    const float* x = X + (size_t)row * 2048;

    float4 v0 = *(const float4*)&x[tid * 8];
    float4 v1 = *(const float4*)&x[tid * 8 + 4];
    float ss = v0.x * v0.x + v0.y * v0.y + v0.z * v0.z + v0.w * v0.w +
               v1.x * v1.x + v1.y * v1.y + v1.z * v1.z + v1.w * v1.w;
    #pragma unroll
    for (int o = 32; o > 0; o >>= 1) ss += __shfl_xor(ss, o);
    __shared__ float wsum[4];
    if ((tid & 63) == 0) wsum[tid >> 6] = ss;
    __syncthreads();
    const float inv = 1.0f / sqrtf((wsum[0] + wsum[1] + wsum[2] + wsum[3]) *
                                   (1.0f / 2048.0f) + EPSF);

    float4 ga = *(const float4*)&g[tid * 8];
    float4 gb = *(const float4*)&g[tid * 8 + 4];
    const float y[8] = {v0.x * ga.x * inv, v0.y * ga.y * inv, v0.z * ga.z * inv,
                        v0.w * ga.w * inv, v1.x * gb.x * inv, v1.y * gb.y * inv,
                        v1.z * gb.z * inv, v1.w * gb.w * inv};
    u32x4 p0, p1;
    p0.x = packsplit(y[0]); p0.y = packsplit(y[1]);
    p0.z = packsplit(y[2]); p0.w = packsplit(y[3]);
    p1.x = packsplit(y[4]); p1.y = packsplit(y[5]);
    p1.z = packsplit(y[6]); p1.w = packsplit(y[7]);
    const size_t base = (size_t)row * 2048 + tid * 8;
    *(u32x4*)&Yp[base] = p0;
    *(u32x4*)&Yp[base + 4] = p1;
}

// ---------------- MFMA GEMM: C[M,N] = A[M,K] * B[N,K]^T -------------------
// A: packed split-bf16 u32 [M,K]. B: fp32 [N,K] (split in-register at stage).
// 128x128 tile, BK=32, 256 thr = 4 waves (2x2 of 64x64), 16x16x32 bf16 MFMA.
// EPI=0: C[idx] = acc (+ R[idx] if R)
// EPI=1: a=C[idx]; ((u32*)C)[idx] = packsplit(silu(a)*acc)   [in place]
// EPI=2: write packed TRANSPOSED: Vt[((b*16+h)*128+dl)*2048 + s] (C = Vt)
template<int EPI>
__global__ __launch_bounds__(256) void gemm_pk(const u32* __restrict__ Ap,
                                               const float* __restrict__ B,
                                               const float* __restrict__ R,
                                               float* __restrict__ C,
                                               int M, int N, int K) {
    __shared__ __align__(16) u16 sAh[4096];  // [128 rows][32 k]
    __shared__ __align__(16) u16 sAl[4096];
    __shared__ __align__(16) u16 sBh[4096];
    __shared__ __align__(16) u16 sBl[4096];
    const int tid = threadIdx.x;
    const int wid = tid >> 6, lane = tid & 63;

    // XCD-aware swizzle (T1): bijective iff nwg%8==0.
    int bx = blockIdx.x, by = blockIdx.y;
    {
        const int nwg = gridDim.x * gridDim.y;
        if ((nwg & 7) == 0) {
            const int wgid = by * gridDim.x + bx;
            const int chunk = nwg >> 3;
            const int swz = (wgid & 7) * chunk + (wgid >> 3);
            bx = swz % gridDim.x;
            by = swz / gridDim.x;
        }
    }
    const int m0 = by * 128, n0 = bx * 128;
    const int wm = wid >> 1, wn = wid & 1;
    const int lr = lane & 15;          // fragment row (A) / col (B)
    const int lk = (lane >> 4) * 8;    // k-octet

    f32x4 acc[4][4];
    #pragma unroll
    for (int i = 0; i < 4; ++i)
        #pragma unroll
        for (int j = 0; j < 4; ++j) {
            acc[i][j].x = 0.f; acc[i][j].y = 0.f;
            acc[i][j].z = 0.f; acc[i][j].w = 0.f;
        }

    u32x4 pa[4];
    f32x4 vb[4];
    #pragma unroll
    for (int j = 0; j < 4; ++j) {
        const int f = tid + 256 * j, row = f >> 3, c4 = (f & 7) * 4;
        pa[j] = *(const u32x4*)&Ap[(size_t)(m0 + row) * K + c4];
        vb[j] = *(const f32x4*)&B[(size_t)(n0 + row) * K + c4];
    }

    const int nk = K / 32;
    for (int kt = 0; kt < nk; ++kt) {
        #pragma unroll
        for (int j = 0; j < 4; ++j) {
            const int f = tid + 256 * j, row = f >> 3, c4 = (f & 7) * 4;
            const u32x4 p = pa[j];
            u16x4 ah, al;
            ah.x = (u16)(p.x >> 16); al.x = (u16)(p.x & 0xFFFFu);
            ah.y = (u16)(p.y >> 16); al.y = (u16)(p.y & 0xFFFFu);
            ah.z = (u16)(p.z >> 16); al.z = (u16)(p.z & 0xFFFFu);
            ah.w = (u16)(p.w >> 16); al.w = (u16)(p.w & 0xFFFFu);
            *(u16x4*)&sAh[row * 32 + c4] = ah;
            *(u16x4*)&sAl[row * 32 + c4] = al;
            const f32x4 v = vb[j];
            u16x4 bh, bl;
            bh.x = f2bf(v.x); bl.x = f2bf(v.x - bf2f(bh.x));
            bh.y = f2bf(v.y); bl.y = f2bf(v.y - bf2f(bh.y));
            bh.z = f2bf(v.z); bl.z = f2bf(v.z - bf2f(bh.z));
            bh.w = f2bf(v.w); bl.w = f2bf(v.w - bf2f(bh.w));
            *(u16x4*)&sBh[row * 32 + c4] = bh;
            *(u16x4*)&sBl[row * 32 + c4] = bl;
        }
        __syncthreads();

        if (kt + 1 < nk) {
            const int k0 = (kt + 1) * 32;
            #pragma unroll
            for (int j = 0; j < 4; ++j) {
                const int f = tid + 256 * j, row = f >> 3, c4 = (f & 7) * 4;
                pa[j] = *(const u32x4*)&Ap[(size_t)(m0 + row) * K + k0 + c4];
                vb[j] = *(const f32x4*)&B[(size_t)(n0 + row) * K + k0 + c4];
            }
        }

        s16x8 fah[4], fal[4], fbh[4], fbl[4];
        #pragma unroll
        for (int i = 0; i < 4; ++i) {
            const int ra = (wm * 64 + i * 16 + lr) * 32 + lk;
            const int rb = (wn * 64 + i * 16 + lr) * 32 + lk;
            fah[i] = *(const s16x8*)&sAh[ra];
            fal[i] = *(const s16x8*)&sAl[ra];
            fbh[i] = *(const s16x8*)&sBh[rb];
            fbl[i] = *(const s16x8*)&sBl[rb];
        }
        #pragma unroll
        for (int i = 0; i < 4; ++i)
            #pragma unroll
            for (int j = 0; j < 4; ++j) {
                acc[i][j] = __builtin_amdgcn_mfma_f32_16x16x32_bf16(fah[i], fbh[j], acc[i][j], 0, 0, 0);
                acc[i][j] = __builtin_amdgcn_mfma_f32_16x16x32_bf16(fah[i], fbl[j], acc[i][j], 0, 0, 0);
                acc[i][j] = __builtin_amdgcn_mfma_f32_16x16x32_bf16(fal[i], fbh[j], acc[i][j], 0, 0, 0);
            }
        __syncthreads();
    }

    // C/D layout (m89/m91): col = lane&15, row = (lane>>4)*4 + reg
    const int orow = (lane >> 4) * 4, ocol = lane & 15;
    #pragma unroll
    for (int i = 0; i < 4; ++i)
        #pragma unroll
        for (int j = 0; j < 4; ++j) {
            const int col = n0 + wn * 64 + j * 16 + ocol;
            if (EPI == 2) {
                // packed transposed V write: row0 -> (b, s0..s0+3) contiguous
                const int row0 = m0 + wm * 64 + i * 16 + orow;
                const int b = row0 >> 11, s = row0 & 2047;
                const int h = col >> 7, dl = col & 127;
                u32x4 pk;
                pk.x = packsplit(acc[i][j][0]);
                pk.y = packsplit(acc[i][j][1]);
                pk.z = packsplit(acc[i][j][2]);
                pk.w = packsplit(acc[i][j][3]);
                u32* VtC = (u32*)C;
                *(u32x4*)&VtC[((size_t)((b * 16 + h) * 128 + dl)) * 2048 + s] = pk;
            } else {
                #pragma unroll
                for (int rI = 0; rI < 4; ++rI) {
                    const int row = m0 + wm * 64 + i * 16 + orow + rI;
                    const size_t idx = (size_t)row * N + col;
                    const float v = acc[i][j][rI];
                    if (EPI == 0) {
                        C[idx] = R ? v + R[idx] : v;
                    } else {
                        const float aval = C[idx];
                        const float prod = aval / (1.f + __expf(-aval)) * v;
                        ((u32*)C)[idx] = packsplit(prod);
                    }
                }
            }
        }
}

// ---------------- RoPE table ------------------------------------------------
__global__ __launch_bounds__(256) void rope_table_k(float2* __restrict__ tab, int S) {
    const int idx = blockIdx.x * blockDim.x + threadIdx.x;
    if (idx >= S * 64) return;
    const int s = idx >> 6;
    const int i = idx & 63;
    const float inv_freq = (float)(1.0 / pow(10000.0, (double)(2 * i) / 128.0));
    const float a = (float)s * inv_freq;
    tab[idx] = make_float2(sinf(a), cosf(a));
}

// ---------------- RoPE apply: Q in place (fp32) -----------------------------
__global__ __launch_bounds__(256) void rope_apply_k(float* __restrict__ X,
                                                    const float2* __restrict__ tab,
                                                    int S) {
    const int idx = blockIdx.x * blockDim.x + threadIdx.x;  // over B*S*H*64
    const int i = idx & 63;
    const int h = (idx >> 6) & 15;
    const int bs = idx >> 10;
    const int s = bs & (S - 1);
    const float2 sc = tab[s * 64 + i];
    const size_t base = (size_t)bs * 2048 + h * 128 + 2 * i;
    float2 v = *(float2*)&X[base];
    float2 o;
    o.x = v.x * sc.y - v.y * sc.x;
    o.y = v.x * sc.x + v.y * sc.y;
    *(float2*)&X[base] = o;
}

// ---------------- RoPE apply + pack: K in place (fp32 -> packed u32) --------
__global__ __launch_bounds__(256) void rope_pack_k(float* __restrict__ X,
                                                   const float2* __restrict__ tab,
                                                   int S) {
    const int idx = blockIdx.x * blockDim.x + threadIdx.x;
    const int i = idx & 63;
    const int h = (idx >> 6) & 15;
    const int bs = idx >> 10;
    const int s = bs & (S - 1);
    const float2 sc = tab[s * 64 + i];
    const size_t base = (size_t)bs * 2048 + h * 128 + 2 * i;
    float2 v = *(float2*)&X[base];
    const float ox = v.x * sc.y - v.y * sc.x;
    const float oy = v.x * sc.x + v.y * sc.y;
    u32* p = (u32*)&X[base];   // same bytes, same thread -> race-free
    p[0] = packsplit(ox);
    p[1] = packsplit(oy);
}

// ---------------- MFMA flash attention (split-bf16, causal) -----------------
// Block: 4 waves, Q-tile 64 (wave w owns q rows q0+w*16..+16), KV tile 32.
// Q fp32 [bs][2048] (split in reg); K packed u32 [bs][2048];
// V packed TRANSPOSED u32 [bh][128][2048]. Out: packed ctx [bs][2048].
#define SKR 136   // sK row stride (u16): 272B, 16B-aligned
#define SVR 40    // sVt row stride (u16): 80B
#define SPR 40    // sP row stride (u16): 80B

__global__ __launch_bounds__(256) void flash_mfma_k(const float* __restrict__ Q,
                                                    const u32* __restrict__ Kp,
                                                    const u32* __restrict__ Vt,
                                                    u32* __restrict__ Op) {
    constexpr int S = 2048, D = 2048;
    __shared__ __align__(16) u16 sKh[32 * SKR], sKl[32 * SKR];
    __shared__ __align__(16) u16 sVh[128 * SVR], sVl[128 * SVR];
    __shared__ __align__(16) u16 sPh[4][16 * SPR], sPl[4][16 * SPR];

    const int tid = threadIdx.x;
    const int w = tid >> 6, lane = tid & 63;
    const int lr = lane & 15, g = lane >> 4;
    const int q0 = blockIdx.x * 64;
    const int bh = blockIdx.y;
    const size_t headoff = (size_t)(bh >> 4) * S * D + (size_t)(bh & 15) * 128;
    const size_t vbase = (size_t)bh * 128 * S;
    const float scale = 0.088388347648318447f;  // 1/sqrt(128)

    // Q fragments: A row = lr, k = g*8+e within each 32-k step
    s16x8 qh[4], ql[4];
    {
        const float* qp = Q + headoff + (size_t)(q0 + w * 16 + lr) * D;
        #pragma unroll
        for (int kt = 0; kt < 4; ++kt) {
            const int d0 = kt * 32 + g * 8;
            f32x4 a = *(const f32x4*)(qp + d0);
            f32x4 b = *(const f32x4*)(qp + d0 + 4);
            const float v[8] = {a.x, a.y, a.z, a.w, b.x, b.y, b.z, b.w};
            #pragma unroll
            for (int e = 0; e < 8; ++e) {
                const u16 hb = f2bf(v[e]);
                qh[kt][e] = (short)hb;
                ql[kt][e] = (short)f2bf(v[e] - bf2f(hb));
            }
        }
    }

    float m[4], lsum[4];
    #pragma unroll
    for (int r = 0; r < 4; ++r) { m[r] = -INFINITY; lsum[r] = 0.f; }
    f32x4 accO[8];
    #pragma unroll
    for (int nf = 0; nf < 8; ++nf) {
        accO[nf].x = 0.f; accO[nf].y = 0.f; accO[nf].z = 0.f; accO[nf].w = 0.f;
    }

    const int qrow_b = q0 + w * 16 + g * 4;  // D-layout row base (global)
    const int nt = (q0 >> 5) + 2;

    for (int t = 0; t < nt; ++t) {
        const int k0 = t * 32;
        {   // ---- stage K tile: [kv=32][d=128] from packed rows ----
            const int row = tid >> 3, c = (tid & 7) * 16;
            const u32* kp = Kp + headoff + (size_t)(k0 + row) * D + c;
            #pragma unroll
            for (int j = 0; j < 4; ++j) {
                const u32x4 v = *(const u32x4*)(kp + j * 4);
                u16x4 h, l;
                h.x = (u16)(v.x >> 16); l.x = (u16)(v.x & 0xFFFFu);
                h.y = (u16)(v.y >> 16); l.y = (u16)(v.y & 0xFFFFu);
                h.z = (u16)(v.z >> 16); l.z = (u16)(v.z & 0xFFFFu);
                h.w = (u16)(v.w >> 16); l.w = (u16)(v.w & 0xFFFFu);
                *(u16x4*)&sKh[row * SKR + c + j * 4] = h;
                *(u16x4*)&sKl[row * SKR + c + j * 4] = l;
            }
            // ---- stage V tile: [d=128][kv=32] from transposed packed ----
            const int d = tid >> 1, kvh = (tid & 1) * 16;
            const u32* vp = Vt + vbase + (size_t)d * S + k0 + kvh;
            #pragma unroll
            for (int j = 0; j < 4; ++j) {
                const u32x4 v = *(const u32x4*)(vp + j * 4);
                u16x4 h, l;
                h.x = (u16)(v.x >> 16); l.x = (u16)(v.x & 0xFFFFu);
                h.y = (u16)(v.y >> 16); l.y = (u16)(v.y & 0xFFFFu);
                h.z = (u16)(v.z >> 16); l.z = (u16)(v.z & 0xFFFFu);
                h.w = (u16)(v.w >> 16); l.w = (u16)(v.w & 0xFFFFu);
                *(u16x4*)&sVh[d * SVR + kvh + j * 4] = h;
                *(u16x4*)&sVl[d * SVR + kvh + j * 4] = l;
            }
        }
        __syncthreads();

        // ---- QK^T: D[16q x 32kv], split 3-MFMA ----
        f32x4 sc0, sc1;
        sc0.x = 0.f; sc0.y = 0.f; sc0.z = 0.f; sc0.w = 0.f;
        sc1 = sc0;
        #pragma unroll
        for (int kt = 0; kt < 4; ++kt) {
            const int o0 = lr * SKR + kt * 32 + g * 8;
            const int o1 = (16 + lr) * SKR + kt * 32 + g * 8;
            const s16x8 k0h = *(const s16x8*)&sKh[o0];
            const s16x8 k0l = *(const s16x8*)&sKl[o0];
            const s16x8 k1h = *(const s16x8*)&sKh[o1];
            const s16x8 k1l = *(const s16x8*)&sKl[o1];
            sc0 = __builtin_amdgcn_mfma_f32_16x16x32_bf16(qh[kt], k0h, sc0, 0, 0, 0);
            sc0 = __builtin_amdgcn_mfma_f32_16x16x32_bf16(qh[kt], k0l, sc0, 0, 0, 0);
            sc0 = __builtin_amdgcn_mfma_f32_16x16x32_bf16(ql[kt], k0h, sc0, 0, 0, 0);
            sc1 = __builtin_amdgcn_mfma_f32_16x16x32_bf16(qh[kt], k1h, sc1, 0, 0, 0);
            sc1 = __builtin_amdgcn_mfma_f32_16x16x32_bf16(qh[kt], k1l, sc1, 0, 0, 0);
            sc1 = __builtin_amdgcn_mfma_f32_16x16x32_bf16(ql[kt], k1h, sc1, 0, 0, 0);
        }

        // ---- mask + online softmax (rows = qrow_b + r, cols = k0+{lr,16+lr})
        float p0[4], p1[4], corr[4];
        #pragma unroll
        for (int r = 0; r < 4; ++r) {
            const int qr = qrow_b + r;
            float s0 = sc0[r] * scale;
            float s1 = sc1[r] * scale;
            if (k0 + lr > qr) s0 = -INFINITY;
            if (k0 + 16 + lr > qr) s1 = -INFINITY;
            float tm = fmaxf(s0, s1);
            tm = fmaxf(tm, __shfl_xor(tm, 1));
            tm = fmaxf(tm, __shfl_xor(tm, 2));
            tm = fmaxf(tm, __shfl_xor(tm, 4));
            tm = fmaxf(tm, __shfl_xor(tm, 8));
            const float mn = fmaxf(m[r], tm);
            corr[r] = __expf(m[r] - mn);   // first tile: exp(-inf)=0
            m[r] = mn;
            p0[r] = __expf(s0 - mn);       // masked -> 0
            p1[r] = __expf(s1 - mn);
            lsum[r] = lsum[r] * corr[r] + p0[r] + p1[r];
        }
        #pragma unroll
        for (int nf = 0; nf < 8; ++nf) {
            accO[nf].x *= corr[0]; accO[nf].y *= corr[1];
            accO[nf].z *= corr[2]; accO[nf].w *= corr[3];
        }

        // ---- P (split) -> wave-local LDS, reshaped for A-fragments ----
        #pragma unroll
        for (int r = 0; r < 4; ++r) {
            const int rowo = (g * 4 + r) * SPR;
            const u16 h0 = f2bf(p0[r]);
            sPh[w][rowo + lr] = h0;
            sPl[w][rowo + lr] = f2bf(p0[r] - bf2f(h0));
            const u16 h1 = f2bf(p1[r]);
            sPh[w][rowo + 16 + lr] = h1;
            sPl[w][rowo + 16 + lr] = f2bf(p1[r] - bf2f(h1));
        }
        const s16x8 pah = *(const s16x8*)&sPh[w][lr * SPR + g * 8];
        const s16x8 pal = *(const s16x8*)&sPl[w][lr * SPR + g * 8];

        // ---- PV: O[16q x 128d] += P[16x32] * V[32x128] ----
        #pragma unroll
        for (int nf = 0; nf < 8; ++nf) {
            const int o = (nf * 16 + lr) * SVR + g * 8;
            const s16x8 vh = *(const s16x8*)&sVh[o];
            const s16x8 vl = *(const s16x8*)&sVl[o];
            accO[nf] = __builtin_amdgcn_mfma_f32_16x16x32_bf16(pah, vh, accO[nf], 0, 0, 0);
            accO[nf] = __builtin_amdgcn_mfma_f32_16x16x32_bf16(pah, vl, accO[nf], 0, 0, 0);
            accO[nf] = __builtin_amdgcn_mfma_f32_16x16x32_bf16(pal, vh, accO[nf], 0, 0, 0);
        }
        __syncthreads();
    }

    // ---- finalize: reduce l across 16-lane group, normalize, pack out ----
    #pragma unroll
    for (int r = 0; r < 4; ++r) {
        float t = lsum[r];
        t += __shfl_xor(t, 1);
        t += __shfl_xor(t, 2);
        t += __shfl_xor(t, 4);
        t += __shfl_xor(t, 8);
        lsum[r] = 1.0f / t;
    }
    #pragma unroll
    for (int nf = 0; nf < 8; ++nf)
        #pragma unroll
        for (int r = 0; r < 4; ++r) {
            Op[headoff + (size_t)(qrow_b + r) * D + nf * 16 + lr] =
                packsplit(accO[nf][r] * lsum[r]);
        }
}

// ---------------------------------------------------------------------------
extern "C" void kernel_launch(void* const* d_in, const int* in_sizes, int n_in,
                              void* d_out, int out_size, void* d_ws, size_t ws_size,
                              hipStream_t stream) {
    (void)in_sizes; (void)n_in; (void)out_size; (void)ws_size;
    const float* x  = (const float*)d_in[0];
    const float* Wq = (const float*)d_in[1];
    const float* Wk = (const float*)d_in[2];
    const float* Wv = (const float*)d_in[3];
    const float* Wo = (const float*)d_in[4];
    const float* W1 = (const float*)d_in[5];
    const float* W2 = (const float*)d_in[6];
    const float* W3 = (const float*)d_in[7];
    const float* g1 = (const float*)d_in[8];
    const float* g2 = (const float*)d_in[9];
    float* out = (float*)d_out;

    constexpr int Bt = 2, S = 2048, Dm = 2048, Hh = 16, Dff = 5632;
    constexpr int M = Bt * S;                  // 4096
    constexpr size_t MD = (size_t)M * Dm;      // 8.39M elems

    // -------- workspace (~135 MB) ------------------------------------------
    char* w = (char*)d_ws;
    size_t off = 0;
    auto alloc = [&](size_t bytes) -> void* {
        void* p = w + off;
        off += (bytes + 255) & ~(size_t)255;
        return p;
    };
    u32*   xnp = (u32*)alloc(MD * 4);      // 33.6 MB; also ctx (packed)
    float* Qb  = (float*)alloc(MD * 4);    // 33.6 MB \  Q fp32; FFN 'a' reuses
    float* Kb  = (float*)alloc(MD * 4);    // 33.6 MB  | K fp32 -> packed
    u32*   Vtb = (u32*)alloc(MD * 4);      // 33.6 MB /  V packed transposed
    float2* tab = (float2*)alloc((size_t)S * 64 * 8);  // 1 MB
    u32*   ctxp = xnp;                     // attn out over xn (dead post-QKV)
    float* ab   = Qb;                      // FFN 'a' over Q/K/Vt (dead post-attn)
    u32*   abp  = (u32*)Qb;                // silu product packed over 'a'

    // 1. rmsnorm(x, g1) -> xnp (packed)
    rmsnorm_pack_k<<<M, 256, 0, stream>>>(x, g1, xnp);

    // 2. Q/K fp32; V directly packed-transposed (EPI=2)
    dim3 gqkv(Dm / 128, M / 128);
    gemm_pk<0><<<gqkv, 256, 0, stream>>>(xnp, Wq, nullptr, Qb, M, Dm, Dm);
    gemm_pk<0><<<gqkv, 256, 0, stream>>>(xnp, Wk, nullptr, Kb, M, Dm, Dm);
    gemm_pk<2><<<gqkv, 256, 0, stream>>>(xnp, Wv, nullptr, (float*)Vtb, M, Dm, Dm);

    // 3. RoPE: Q in place (fp32); K in place -> packed
    rope_table_k<<<(S * 64) / 256, 256, 0, stream>>>(tab, S);
    const int ropeN = M * Hh * 64;
    rope_apply_k<<<ropeN / 256, 256, 0, stream>>>(Qb, tab, S);
    rope_pack_k<<<ropeN / 256, 256, 0, stream>>>(Kb, tab, S);

    // 4. MFMA flash attention -> ctxp (packed, merged-head [B*S, D])
    flash_mfma_k<<<dim3(S / 64, Bt * Hh), 256, 0, stream>>>(Qb, (const u32*)Kb, Vtb, ctxp);

    // 5. x2 = x + ctx @ Wo^T -> out
    gemm_pk<0><<<gqkv, 256, 0, stream>>>(ctxp, Wo, x, out, M, Dm, Dm);

    // 6. rmsnorm(x2, g2) -> xnp (ctx dead)
    rmsnorm_pack_k<<<M, 256, 0, stream>>>(out, g2, xnp);

    // 7. FFN a = xn @ W1^T (fp32, over dead Q/K/Vt region)
    dim3 gff(Dff / 128, M / 128);
    gemm_pk<0><<<gff, 256, 0, stream>>>(xnp, W1, nullptr, ab, M, Dff, Dm);

    // 8. gate = xn @ W3^T, fused: reads a, writes packsplit(silu(a)*gate)
    gemm_pk<1><<<gff, 256, 0, stream>>>(xnp, W3, nullptr, ab, M, Dff, Dm);

    // 9. out = x2 + product @ W2^T (in-place residual)
    gemm_pk<0><<<gqkv, 256, 0, stream>>>(abp, W2, out, out, M, Dm, Dff);
}